// Round 1
// baseline (997.951 us; speedup 1.0000x reference)
//
#include <hip/hip_runtime.h>
#include <math.h>

// Problem constants: B=16, N=325, H=8, L=24, DK=DV=64
#define NB   16
#define NN   325
#define NH   8
#define LL   24
#define DK   64
#define DV   64
#define NG   (NB * NN * NH)          // 41600 independent (b,n,h) tiles
#define SSTR 28                      // score-tile row stride: mult of 4 (aligned float4), ≤2-way banks

__device__ __forceinline__ float dot4(float4 a, float4 b) {
    return a.x * b.x + a.y * b.y + a.z * b.z + a.w * b.w;
}

// One wave (64 threads) per (b,n,h) tile. Single-wave workgroup => __syncthreads()
// is a compiler fence with a trivially-satisfied barrier: no cross-wave drain,
// no idle-lane phases.
__global__ __launch_bounds__(64) void tatt_kernel(
    const float* __restrict__ Q, const float* __restrict__ K,
    const float* __restrict__ V, const float* __restrict__ Mask,
    const float* __restrict__ Res, float* __restrict__ outC,
    float* __restrict__ outS)
{
    __shared__ __align__(16) float sS[LL * SSTR];  // 2688 B: scores -> attn (in place)
    __shared__ __align__(16) float sM[LL];         // per-column (k) max over q
    __shared__ __align__(16) float sI[LL];         // per-column (k) 1/sum

    const int g    = blockIdx.x;
    const int lane = threadIdx.x;

    const float* Qg = Q    + (size_t)g * (LL * DK);
    const float* Kg = K    + (size_t)g * (LL * DK);
    const float* Vg = V    + (size_t)g * (LL * DV);
    const float* Mg = Mask + (size_t)g * (LL * LL);
    const float* Rg = Res  + (size_t)g * (LL * LL);
    float*       Cg = outC + (size_t)g * (LL * DV);
    float*       Sg = outS + (size_t)g * (LL * LL);

    // ---- Phase A: raw QK^T, 3x3 register tile per lane, direct from global.
    // Lanes sharing a q-group (8x) / k-group (8x) read identical addresses ->
    // VMEM coalescer dedups; each tile element fetched once per wave.
    {
        const int q0 = (lane >> 3) * 3;
        const int k0 = (lane & 7) * 3;
        const float* qp = Qg + q0 * DK;
        const float* kp = Kg + k0 * DK;
        float a00 = 0.f, a01 = 0.f, a02 = 0.f;
        float a10 = 0.f, a11 = 0.f, a12 = 0.f;
        float a20 = 0.f, a21 = 0.f, a22 = 0.f;
        #pragma unroll 4
        for (int d = 0; d < DK; d += 4) {
            float4 qv0 = *(const float4*)(qp + d);
            float4 qv1 = *(const float4*)(qp + DK + d);
            float4 qv2 = *(const float4*)(qp + 2 * DK + d);
            float4 kv0 = *(const float4*)(kp + d);
            float4 kv1 = *(const float4*)(kp + DK + d);
            float4 kv2 = *(const float4*)(kp + 2 * DK + d);
            a00 += dot4(qv0, kv0); a01 += dot4(qv0, kv1); a02 += dot4(qv0, kv2);
            a10 += dot4(qv1, kv0); a11 += dot4(qv1, kv1); a12 += dot4(qv1, kv2);
            a20 += dot4(qv2, kv0); a21 += dot4(qv2, kv1); a22 += dot4(qv2, kv2);
        }
        float* p0 = sS + (q0 + 0) * SSTR + k0;
        float* p1 = sS + (q0 + 1) * SSTR + k0;
        float* p2 = sS + (q0 + 2) * SSTR + k0;
        p0[0] = a00; p0[1] = a01; p0[2] = a02;
        p1[0] = a10; p1[1] = a11; p1[2] = a12;
        p2[0] = a20; p2[1] = a21; p2[2] = a22;
    }
    __syncthreads();

    // ---- Phase B: linear-layout pass. 144 float4 = 576 elems; lanes take
    // idx = lane, lane+64, and (lane<16) lane+128. Mask/Res loads and the S
    // global store are fully coalesced float4. Keep s in registers for Phase D.
    float4 s40, s41, s42 = make_float4(0.f, 0.f, 0.f, 0.f);
    #define PHASE_B(I0, DST) { \
        const int i0_ = (I0); \
        const int q_ = i0_ / 24, kk_ = i0_ - q_ * 24; \
        float4 p_  = *(const float4*)(sS + q_ * SSTR + kk_); \
        float4 r_  = *(const float4*)(Rg + i0_); \
        float4 mm_ = *(const float4*)(Mg + i0_); \
        float4 s_; \
        s_.x = (mm_.x > 0.5f) ? -1e9f : fmaf(p_.x, 0.125f, r_.x); \
        s_.y = (mm_.y > 0.5f) ? -1e9f : fmaf(p_.y, 0.125f, r_.y); \
        s_.z = (mm_.z > 0.5f) ? -1e9f : fmaf(p_.z, 0.125f, r_.z); \
        s_.w = (mm_.w > 0.5f) ? -1e9f : fmaf(p_.w, 0.125f, r_.w); \
        *(float4*)(Sg + i0_) = s_; \
        *(float4*)(sS + q_ * SSTR + kk_) = s_; \
        DST = s_; }

    PHASE_B(lane * 4, s40);
    PHASE_B(lane * 4 + 256, s41);
    if (lane < 16) { PHASE_B(lane * 4 + 512, s42); }
    __syncthreads();

    // ---- Phase C: softmax stats over q (axis=3!) per column k.
    // 2 lanes per column, 12 rows each, shfl_xor(1) combine.
    if (lane < 48) {
        const int k = lane >> 1;
        const float* cp = sS + (lane & 1) * (12 * SSTR) + k;
        float vv[12];
        #pragma unroll
        for (int j = 0; j < 12; ++j) vv[j] = cp[j * SSTR];
        float m = vv[0];
        #pragma unroll
        for (int j = 1; j < 12; ++j) m = fmaxf(m, vv[j]);
        m = fmaxf(m, __shfl_xor(m, 1));
        float sum = 0.f;
        #pragma unroll
        for (int j = 0; j < 12; ++j) sum += __expf(vv[j] - m);
        sum += __shfl_xor(sum, 1);
        if ((lane & 1) == 0) {
            sM[k] = m;
            sI[k] = 1.f / sum;
        }
    }
    __syncthreads();

    // ---- Phase D: A = exp(S - m_col) * inv_col, scores kept in registers,
    // m/inv read as aligned float4 (kk_ is a multiple of 4).
    #define PHASE_D(I0, SV) { \
        const int i0_ = (I0); \
        const int q_ = i0_ / 24, kk_ = i0_ - q_ * 24; \
        float4 m_ = *(const float4*)(sM + kk_); \
        float4 j_ = *(const float4*)(sI + kk_); \
        float4 a_; \
        a_.x = __expf(SV.x - m_.x) * j_.x; \
        a_.y = __expf(SV.y - m_.y) * j_.y; \
        a_.z = __expf(SV.z - m_.z) * j_.z; \
        a_.w = __expf(SV.w - m_.w) * j_.w; \
        *(float4*)(sS + q_ * SSTR + kk_) = a_; }

    PHASE_D(lane * 4, s40);
    PHASE_D(lane * 4 + 256, s41);
    if (lane < 16) { PHASE_D(lane * 4 + 512, s42); }
    __syncthreads();

    // ---- Phase E: C[q][v] = sum_k A[q][k] * V[k][v].
    // Lane = (qs: 4 groups of 6 rows) x (vq: 16 float4 columns).
    // A rows read as ds_read_b128 (4 distinct addrs, 16-way broadcast: conflict-free);
    // V direct from global (16 distinct float4, 4-way broadcast).
    {
        const int v0c = (lane & 15) * 4;
        const int qb  = (lane >> 4) * 6;
        const float* sA = sS + qb * SSTR;
        float4 o0 = {0,0,0,0}, o1 = {0,0,0,0}, o2 = {0,0,0,0};
        float4 o3 = {0,0,0,0}, o4 = {0,0,0,0}, o5 = {0,0,0,0};
        #define PV_STEP(COMP, J) { \
            float4 vv = *(const float4*)(vp + (J) * DV); \
            o0.x += a0.COMP * vv.x; o0.y += a0.COMP * vv.y; o0.z += a0.COMP * vv.z; o0.w += a0.COMP * vv.w; \
            o1.x += a1.COMP * vv.x; o1.y += a1.COMP * vv.y; o1.z += a1.COMP * vv.z; o1.w += a1.COMP * vv.w; \
            o2.x += a2.COMP * vv.x; o2.y += a2.COMP * vv.y; o2.z += a2.COMP * vv.z; o2.w += a2.COMP * vv.w; \
            o3.x += a3.COMP * vv.x; o3.y += a3.COMP * vv.y; o3.z += a3.COMP * vv.z; o3.w += a3.COMP * vv.w; \
            o4.x += a4.COMP * vv.x; o4.y += a4.COMP * vv.y; o4.z += a4.COMP * vv.z; o4.w += a4.COMP * vv.w; \
            o5.x += a5.COMP * vv.x; o5.y += a5.COMP * vv.y; o5.z += a5.COMP * vv.z; o5.w += a5.COMP * vv.w; }
        #pragma unroll
        for (int kk = 0; kk < LL; kk += 4) {
            float4 a0 = *(const float4*)(sA + 0 * SSTR + kk);
            float4 a1 = *(const float4*)(sA + 1 * SSTR + kk);
            float4 a2 = *(const float4*)(sA + 2 * SSTR + kk);
            float4 a3 = *(const float4*)(sA + 3 * SSTR + kk);
            float4 a4 = *(const float4*)(sA + 4 * SSTR + kk);
            float4 a5 = *(const float4*)(sA + 5 * SSTR + kk);
            const float* vp = Vg + kk * DV + v0c;
            PV_STEP(x, 0)
            PV_STEP(y, 1)
            PV_STEP(z, 2)
            PV_STEP(w, 3)
        }
        *(float4*)(Cg + (qb + 0) * DV + v0c) = o0;
        *(float4*)(Cg + (qb + 1) * DV + v0c) = o1;
        *(float4*)(Cg + (qb + 2) * DV + v0c) = o2;
        *(float4*)(Cg + (qb + 3) * DV + v0c) = o3;
        *(float4*)(Cg + (qb + 4) * DV + v0c) = o4;
        *(float4*)(Cg + (qb + 5) * DV + v0c) = o5;
    }
}

extern "C" void kernel_launch(void* const* d_in, const int* in_sizes, int n_in,
                              void* d_out, int out_size, void* d_ws, size_t ws_size,
                              hipStream_t stream) {
    const float* Q    = (const float*)d_in[0];
    const float* K    = (const float*)d_in[1];
    const float* V    = (const float*)d_in[2];
    const float* Mask = (const float*)d_in[3];
    const float* Res  = (const float*)d_in[4];
    float* outC = (float*)d_out;                              // context: G*L*DV
    float* outS = (float*)d_out + (size_t)NG * LL * DV;       // scores:  G*L*L
    hipLaunchKernelGGL(tatt_kernel, dim3(NG), dim3(64), 0, stream,
                       Q, K, V, Mask, Res, outC, outS);
}